// Round 4
// baseline (1402.944 us; speedup 1.0000x reference)
//
#include <hip/hip_runtime.h>

// MSDNet on gfx950 — round 16: fuse the 30 depth kernels with a barrier that
// NEVER touches L2. R13's fusion failed because per-block agent release/
// acquire = 512 full L2 wb/inv walks per depth (FETCH 449GB-class, 907us).
// R15 (391us) showed ~200us of the remaining time is 30x launch overhead
// (ramp + drain + runtime end-of-kernel L2 flush). Design:
//  - XCD band swizzle => ~96% of inter-depth communication is intra-XCD L2.
//  - Cross-band rows (|row - band edge| < D <= 10): merge double-stores
//    (plain + system-scope sc0sc1 -> L3); readers of crossing +-D rows use
//    system-scope loads (bypass L1/L2, always fresh from L3).
//  - Barrier: tree of RELAXED agent atomics (32 leaves -> root; no cache
//    maintenance), s_sleep spin on system-scope load, then plain buffer_inv
//    (L0/L1-only) — same-CU waves can hold stale L1 lines of a pair-plane
//    rewritten last depth. L2 is never written back or invalidated.
//  - Guard: blocks verify s_getreg(HW_REG_XCC_ID) == bid&7; mismatch flips
//    a flag -> all +-D traffic goes system-scope (slow but correct).
//  - hipLaunchCooperativeKernel; on error, fall back to R15's 33-launch path.
// Depth bodies are bit-identical R15 arithmetic (spans, A/B pipeline).

#define MSD_DEPTH 30
#define NB 4
#define IH 512
#define IW 512
#define HALO 16
#define WPp (IW + 2 * HALO)               /* 544 u32 per row */
#define HPp (IH + 2 * HALO)               /* 544 rows */
#define PLANE_U ((size_t)WPp * HPp)       /* u32 per subplane */
#define PSTR ((size_t)NB * PLANE_U)       /* pair stride (u32) */
#define NPAIR 15
#define NPIX (NB * IH * IW)
#define WPK_OFF ((size_t)20 << 20)        /* u32 offset: 80 MB into ws */
#define ZSTRIPS (32 * (WPp / 4) * NPAIR * NB)   /* top/bot: 261120 uint4 */
#define SSTRIPS (512 * 8 * NPAIR * NB)          /* sides:   245760 uint4 */
#define TOTZ (ZSTRIPS + SSTRIPS)
#define NBLK 1024
#define TPB 128

typedef _Float16 h2v __attribute__((ext_vector_type(2)));
typedef unsigned int u32;

__device__ __forceinline__ float fdot2u(u32 a, u32 b, float c) {
#if __has_builtin(__builtin_amdgcn_fdot2)
    return __builtin_amdgcn_fdot2(__builtin_bit_cast(h2v, a),
                                  __builtin_bit_cast(h2v, b), c, false);
#else
    h2v x = __builtin_bit_cast(h2v, a), y = __builtin_bit_cast(h2v, b);
    return c + (float)x[0] * (float)y[0] + (float)x[1] * (float)y[1];
#endif
}

// ---------------------------------------------------------------------------
// Preamble: pack weights + zero halos (rows AND side cols) + scale input +
// zero barrier counters. All writes disjoint. Separate launch => its end-of-
// kernel release flushes L2, so the fused kernel sees everything in L3/HBM.
// ---------------------------------------------------------------------------
__global__ __launch_bounds__(256) void preamble_kernel(const float* __restrict__ x,
                                                       const float* __restrict__ Wmsd,
                                                       const float* __restrict__ convW,
                                                       u32* __restrict__ feats,
                                                       u32* __restrict__ wpk,
                                                       u32* __restrict__ cpk,
                                                       const float* __restrict__ sw,
                                                       const float* __restrict__ sb) {
    int idx = blockIdx.x * 256 + threadIdx.x;

    if (idx < 64) wpk[8192 + idx] = 0u;   // barrier leaves/root/badmap flag

    if (idx < MSD_DEPTH * NPAIR * 9) {
        int I = idx / (NPAIR * 9);
        int rem = idx - I * (NPAIR * 9);
        int p = rem / 9, t = rem - p * 9;
        int NC = I + 1, c0 = 2 * p, c1 = 2 * p + 1;
        h2v pk;
        pk[0] = (_Float16)((c0 < NC) ? Wmsd[((size_t)I * MSD_DEPTH + c0) * 9 + t] : 0.f);
        pk[1] = (_Float16)((c1 < NC) ? Wmsd[((size_t)I * MSD_DEPTH + c1) * 9 + t] : 0.f);
        wpk[idx] = __builtin_bit_cast(u32, pk);
    }
    if (idx < NPAIR) {
        h2v pk;
        pk[0] = (_Float16)convW[2 * idx];
        pk[1] = (_Float16)convW[2 * idx + 1];
        cpk[idx] = __builtin_bit_cast(u32, pk);
    }

    if (idx < ZSTRIPS) {
        const int per = 32 * (WPp / 4); // 32 rows x 136 uint4 strips = 4352
        int sub = idx / per;
        int s = idx - sub * per;
        int rr = s / 136;
        int c4 = (s - rr * 136) * 4;
        int r = (rr < 16) ? rr : (IH + HALO) + (rr - 16);
        uint4 z = {0, 0, 0, 0};
        *(uint4*)(feats + (size_t)sub * PLANE_U + (size_t)r * WPp + c4) = z;
    } else if (idx < TOTZ) {
        int s = idx - ZSTRIPS;
        int sub = s >> 12;            // / 4096 (= 512 rows * 8 strips)
        int rem = s & 4095;
        int r = HALO + (rem >> 3);    // 16..527
        int e = rem & 7;
        int c4 = (e < 4) ? (e * 4) : (IW + HALO + (e - 4) * 4);
        uint4 z = {0, 0, 0, 0};
        *(uint4*)(feats + (size_t)sub * PLANE_U + (size_t)r * WPp + c4) = z;
    }

    if (idx < NPIX / 8) {
        int pix = idx * 8;
        int b = pix >> 18;
        int y = (pix >> 9) & 511;
        int xx = pix & 511;
        const float sws = sw[0], sbs = sb[0];
        u32 v[8];
#pragma unroll
        for (int j = 0; j < 8; ++j) {
            _Float16 h = (_Float16)(x[pix + j] * sws + sbs);
            v[j] = (u32)__builtin_bit_cast(unsigned short, h);
        }
        u32* q = feats + (size_t)b * PLANE_U + (size_t)(y + HALO) * WPp + HALO + xx;
        *(uint4*)q = *(uint4*)&v[0];
        *(uint4*)(q + 4) = *(uint4*)&v[4];
    }
}

// ---------------------------------------------------------------------------
// Depth body — R15 arithmetic + band-edge system-scope traffic.
// ---------------------------------------------------------------------------
template <int I>
__device__ __forceinline__ void depth_body(int b, int y, int lane, bool safe,
                                           u32* __restrict__ feats,
                                           const u32* __restrict__ wpk,
                                           const u32* __restrict__ cpk,
                                           const float* __restrict__ bias,
                                           const float* __restrict__ convW,
                                           const float* __restrict__ convB,
                                           const float* __restrict__ soutw,
                                           const float* __restrict__ soutb,
                                           float* __restrict__ out) {
    constexpr int D = (I % 10) + 1;
    constexpr int NC = I + 1;
    constexpr int NP = (NC + 1) / 2;
    constexpr bool LAST = (I == MSD_DEPTH - 1);
    constexpr int C0 = (12 - D) >> 2;   // D<=4 -> 2, D<=8 -> 1, else 0
    constexpr int C1 = (19 + D) >> 2;   // D<=4 -> 5, D<=8 -> 6, else 7

    const int ybp = y & 255;
    // Does row y-D / y+D live in the OTHER 256-row band (other XCD's L2)?
    // safe mode: any interior row written by another wave -> bypass path.
    const bool xlo = safe ? (y >= D) : (y >= 256 && ybp < D);
    const bool xhi = safe ? (y <= 511 - D) : (y < 256 && ybp >= 256 - D);

    u32* const pb = feats + (size_t)b * PLANE_U + (size_t)(y + HALO) * WPp + HALO + lane * 8;

    float acc[8], ydot[8];
#pragma unroll
    for (int j = 0; j < 8; ++j) { acc[j] = 0.f; ydot[j] = 0.f; }

    const u32* const wrb = wpk + (size_t)I * (NPAIR * 9);

    u32 A[3][32], B[3][32];   // named double buffers (SROA-promoted)

    auto load_row = [&](u32* dst, const u32* rp, bool cross) {
        if (cross) {
#pragma unroll
            for (int c = C0; c <= C1; ++c)
#pragma unroll
                for (int j = 0; j < 4; ++j)
                    dst[4 * c + j] = __hip_atomic_load(
                        (u32*)(rp - 12 + 4 * c + j), __ATOMIC_RELAXED,
                        __HIP_MEMORY_SCOPE_SYSTEM);
        } else {
#pragma unroll
            for (int c = C0; c <= C1; ++c)
                *(uint4*)&dst[4 * c] = *(const uint4*)(rp - 12 + 4 * c);
        }
    };

    auto load_pair = [&](u32 (*bp)[32], int p) {
        const u32* pp = pb + (size_t)p * PSTR;
        load_row(bp[0], pp - (ptrdiff_t)(D * WPp), xlo);
        load_row(bp[1], pp, false);
        load_row(bp[2], pp + (ptrdiff_t)(D * WPp), xhi);
    };

    auto compute = [&](u32 (*bp)[32], int p) {
        const u32* wq = wrb + p * 9; // wave-uniform -> s_load
        const u32 cw = LAST ? cpk[p] : 0u;
#pragma unroll
        for (int r = 0; r < 3; ++r) {
            const u32* s = bp[r];
            const u32 w0 = wq[r * 3 + 0], w1 = wq[r * 3 + 1], w2 = wq[r * 3 + 2];
#pragma unroll
            for (int k = 0; k < 8; ++k) {
                float a = acc[k];
                a = fdot2u(s[12 - D + k], w0, a);   // const idx taps
                a = fdot2u(s[12 + k],     w1, a);
                a = fdot2u(s[12 + D + k], w2, a);
                acc[k] = a;
            }
            if (LAST && r == 1) {
#pragma unroll
                for (int k = 0; k < 8; ++k) ydot[k] = fdot2u(s[12 + k], cw, ydot[k]);
            }
        }
    };

    // 2-deep software pipeline over channel pairs (R12/R15-verified).
    load_pair(A, 0);
    int p = 0;
    for (; p + 2 <= NP; p += 2) {
        load_pair(B, p + 1);
        compute(A, p);
        if (p + 2 < NP) load_pair(A, p + 2);
        compute(B, p + 1);
    }
    if (p < NP) compute(A, p);

    const float b0 = bias[I];
    if (!LAST) {
        u32 part[8];
        if constexpr ((NC & 1) != 0) {
            const u32* rp = pb + (size_t)(NP - 1) * PSTR;   // own row: L1-fresh
            *(uint4*)&part[0] = *(const uint4*)rp;
            *(uint4*)&part[4] = *(const uint4*)(rp + 4);
        }
        u32 mg[8];
#pragma unroll
        for (int j = 0; j < 8; ++j) {
            float h = acc[j] + b0;
            h = h > 0.f ? h : 0.f;
            u32 h16 = (u32)__builtin_bit_cast(unsigned short, (_Float16)h);
            if constexpr ((NC & 1) != 0)
                mg[j] = (part[j] & 0xFFFFu) | (h16 << 16);
            else
                mg[j] = h16;
        }
        u32* q = feats + (size_t)(NC >> 1) * PSTR + (size_t)b * PLANE_U +
                 (size_t)(y + HALO) * WPp + HALO + lane * 8;
        *(uint4*)q = *(uint4*)&mg[0];
        *(uint4*)(q + 4) = *(uint4*)&mg[4];
        // Band-edge rows are read by the other XCD: push a copy to L3 too
        // (same values -> no ordering hazard with the plain store).
        if (safe || ybp >= 246 || ybp <= 9) {
#pragma unroll
            for (int j = 0; j < 8; ++j)
                __hip_atomic_store(q + j, mg[j], __ATOMIC_RELAXED,
                                   __HIP_MEMORY_SCOPE_SYSTEM);
        }
    } else {
        const float cw30 = convW[MSD_DEPTH];
        const float cb = convB[0], ow = soutw[0], ob = soutb[0];
        float* q = out + ((size_t)b * IH + y) * IW + lane * 8;
        float o[8];
#pragma unroll
        for (int j = 0; j < 8; ++j) {
            float h = acc[j] + b0;
            h = h > 0.f ? h : 0.f;
            float yv = ydot[j] + cw30 * h + cb;
            o[j] = yv * ow + ob;
        }
        *(uint4*)q = *(uint4*)&o[0];
        *(uint4*)(q + 4) = *(uint4*)&o[4];
    }
}

// ---------------------------------------------------------------------------
// Legacy (fallback) depth kernel — exact R15 behavior (edge logic harmless).
// ---------------------------------------------------------------------------
template <int I>
__global__ __launch_bounds__(128, 2) void depth_kernel(u32* __restrict__ feats,
                                                       const u32* __restrict__ wpk,
                                                       const u32* __restrict__ cpk,
                                                       const float* __restrict__ bias,
                                                       const float* __restrict__ convW,
                                                       const float* __restrict__ convB,
                                                       const float* __restrict__ soutw,
                                                       const float* __restrict__ soutb,
                                                       float* __restrict__ out) {
    const int tid = threadIdx.x;
    const int widx = tid >> 6, lane = tid & 63;
    const int bid = blockIdx.x;
    const int xcd = bid & 7;
    const int b = xcd >> 1;
    const int y = (xcd & 1) * 256 + (bid >> 3) * 2 + widx;
    depth_body<I>(b, y, lane, false, feats, wpk, cpk, bias, convW, convB,
                  soutw, soutb, out);
}

// ---------------------------------------------------------------------------
// Grid barrier with NO L2 maintenance: leaf/root relaxed agent atomics,
// system-scope spin (always fresh), then L0/L1-only buffer_inv.
// ---------------------------------------------------------------------------
__device__ __forceinline__ void gbar(u32* bars, u32 n) {
    asm volatile("" ::: "memory");
    __syncthreads();                 // compiler drains vmcnt before s_barrier
    if (threadIdx.x == 0) {
        u32 old = __hip_atomic_fetch_add(&bars[blockIdx.x >> 5], 1u,
                                         __ATOMIC_RELAXED, __HIP_MEMORY_SCOPE_AGENT);
        if (old == n * 32u - 1u)     // last of this leaf's 32 blocks, round n
            __hip_atomic_fetch_add(&bars[32], 1u, __ATOMIC_RELAXED,
                                   __HIP_MEMORY_SCOPE_AGENT);
        while (__hip_atomic_load(&bars[32], __ATOMIC_RELAXED,
                                 __HIP_MEMORY_SCOPE_SYSTEM) < n * 32u)
            __builtin_amdgcn_s_sleep(2);
    }
    __syncthreads();
    asm volatile("buffer_inv" ::: "memory");   // vector L0/L1 invalidate only
    __builtin_amdgcn_sched_barrier(0);
}

// ---------------------------------------------------------------------------
__global__ __launch_bounds__(TPB, 2) void msd_fused(u32* __restrict__ feats,
                                                    const u32* __restrict__ wpk,
                                                    const u32* __restrict__ cpk,
                                                    const float* __restrict__ bias,
                                                    const float* __restrict__ convW,
                                                    const float* __restrict__ convB,
                                                    const float* __restrict__ soutw,
                                                    const float* __restrict__ soutb,
                                                    float* __restrict__ out,
                                                    u32* __restrict__ bars) {
    const int tid = threadIdx.x;
    const int widx = tid >> 6, lane = tid & 63;
    const int bid = blockIdx.x;
    const int xcd = bid & 7;
    const int b = xcd >> 1;
    const int y = (xcd & 1) * 256 + (bid >> 3) * 2 + widx;

    // Verify the bid->XCD round-robin assumption; mismatch => safe mode.
    if (tid == 0) {
        u32 xcc;
        asm volatile("s_getreg_b32 %0, hwreg(HW_REG_XCC_ID)" : "=s"(xcc));
        if ((int)(xcc & 7u) != xcd)
            __hip_atomic_store(&bars[33], 1u, __ATOMIC_RELAXED,
                               __HIP_MEMORY_SCOPE_SYSTEM);
    }
    gbar(bars, 1);
    const bool safe = __hip_atomic_load(&bars[33], __ATOMIC_RELAXED,
                                        __HIP_MEMORY_SCOPE_SYSTEM) != 0;

#define PH(I, n)                                                               \
    depth_body<I>(b, y, lane, safe, feats, wpk, cpk, bias, convW, convB,       \
                  soutw, soutb, out);                                          \
    gbar(bars, n);

    PH(0, 2)   PH(1, 3)   PH(2, 4)   PH(3, 5)   PH(4, 6)
    PH(5, 7)   PH(6, 8)   PH(7, 9)   PH(8, 10)  PH(9, 11)
    PH(10, 12) PH(11, 13) PH(12, 14) PH(13, 15) PH(14, 16)
    PH(15, 17) PH(16, 18) PH(17, 19) PH(18, 20) PH(19, 21)
    PH(20, 22) PH(21, 23) PH(22, 24) PH(23, 25) PH(24, 26)
    PH(25, 27) PH(26, 28) PH(27, 29) PH(28, 30)
#undef PH
    depth_body<29>(b, y, lane, safe, feats, wpk, cpk, bias, convW, convB,
                   soutw, soutb, out);
}

// ---------------------------------------------------------------------------
extern "C" void kernel_launch(void* const* d_in, const int* in_sizes, int n_in,
                              void* d_out, int out_size, void* d_ws, size_t ws_size,
                              hipStream_t stream) {
    const float* x     = (const float*)d_in[0];
    const float* Wmsd  = (const float*)d_in[1];
    const float* bias  = (const float*)d_in[2];
    const float* convW = (const float*)d_in[3];
    const float* convB = (const float*)d_in[4];
    const float* sinw  = (const float*)d_in[5];
    const float* sinb  = (const float*)d_in[6];
    const float* soutw = (const float*)d_in[7];
    const float* soutb = (const float*)d_in[8];
    float* out = (float*)d_out;

    u32* feats = (u32*)d_ws;                 // 15 pairs x 4 b x 544x544 u32 = 68 MB
    u32* wpk = feats + WPK_OFF;              // 80 MB offset
    u32* cpk = wpk + MSD_DEPTH * NPAIR * 9;
    u32* bars = wpk + 8192;                  // leaf[32], root, badmap flag

    preamble_kernel<<<(TOTZ + 255) / 256, 256, 0, stream>>>(x, Wmsd, convW,
                                                            feats, wpk, cpk,
                                                            sinw, sinb);

    void* args[] = {&feats, &wpk, &cpk, &bias, &convW, &convB,
                    &soutw, &soutb, &out, &bars};
    hipError_t rc = hipLaunchCooperativeKernel(msd_fused, dim3(NBLK), dim3(TPB),
                                               args, 0u, stream);
    if (rc != hipSuccess) {
        (void)hipGetLastError();             // clear sticky error, legacy path
#define LNCH(I) depth_kernel<I><<<1024, 128, 0, stream>>>(feats, wpk, cpk, bias, convW, convB, soutw, soutb, out);
        LNCH(0)  LNCH(1)  LNCH(2)  LNCH(3)  LNCH(4)
        LNCH(5)  LNCH(6)  LNCH(7)  LNCH(8)  LNCH(9)
        LNCH(10) LNCH(11) LNCH(12) LNCH(13) LNCH(14)
        LNCH(15) LNCH(16) LNCH(17) LNCH(18) LNCH(19)
        LNCH(20) LNCH(21) LNCH(22) LNCH(23) LNCH(24)
        LNCH(25) LNCH(26) LNCH(27) LNCH(28) LNCH(29)
#undef LNCH
    }
}

// Round 5
// 400.140 us; speedup vs baseline: 3.5061x; 3.5061x over previous
//
#include <hip/hip_runtime.h>

// MSDNet on gfx950 — round 17. Fusion abandoned after two regressions (R13
// 907us: per-block agent wb/inv storms; R16 1403us: 1.09GB writes/dispatch,
// system-scope + buffer_inv semantics not under control). Trunk = R15's
// verified 33-launch structure (390us). This round cuts memory-pipe traffic
// with numerics-identical changes:
//  (1) exact-union span loads: the 3 tap windows need exactly 8+2D dwords
//      [12-D, 19+D]; load them with 4B-aligned dwordx4(+x2 tail) instead of
//      16B-chunk rounding (16/24/32 dw -> 12..28 dw, -14% L1 traffic).
//  (2) 8-row blocks (512 thr, grid 256, same XCD bands): waves in a block
//      read overlapping row sets -> L1-level sharing cuts L2 traffic.
//  (3) odd-NC merge partner row taken from live A/B registers, not reloaded.
// Layout: feats = 15 channel-pairs (u32 = 2xf16) x 4 batches x 544x544;
// one wave = one 512-px row (8 px/lane); fdot2 contracts 2 ch/px/tap;
// depth 29 fuses 1x1 conv + output affine. Accumulation order unchanged.

#define MSD_DEPTH 30
#define NB 4
#define IH 512
#define IW 512
#define HALO 16
#define WPp (IW + 2 * HALO)               /* 544 u32 per row */
#define HPp (IH + 2 * HALO)               /* 544 rows */
#define PLANE_U ((size_t)WPp * HPp)       /* u32 per subplane */
#define PSTR ((size_t)NB * PLANE_U)       /* pair stride (u32) */
#define NPAIR 15
#define NPIX (NB * IH * IW)
#define WPK_OFF ((size_t)20 << 20)        /* u32 offset: 80 MB into ws */
#define ZSTRIPS (32 * (WPp / 4) * NPAIR * NB)   /* top/bot: 261120 uint4 */
#define SSTRIPS (512 * 8 * NPAIR * NB)          /* sides:   245760 uint4 */
#define TOTZ (ZSTRIPS + SSTRIPS)

typedef _Float16 h2v __attribute__((ext_vector_type(2)));
typedef unsigned int u32;

__device__ __forceinline__ float fdot2u(u32 a, u32 b, float c) {
#if __has_builtin(__builtin_amdgcn_fdot2)
    return __builtin_amdgcn_fdot2(__builtin_bit_cast(h2v, a),
                                  __builtin_bit_cast(h2v, b), c, false);
#else
    h2v x = __builtin_bit_cast(h2v, a), y = __builtin_bit_cast(h2v, b);
    return c + (float)x[0] * (float)y[0] + (float)x[1] * (float)y[1];
#endif
}

// ---------------------------------------------------------------------------
// Preamble: pack weights + zero halos (rows AND side cols) + scale input.
// ---------------------------------------------------------------------------
__global__ __launch_bounds__(256) void preamble_kernel(const float* __restrict__ x,
                                                       const float* __restrict__ Wmsd,
                                                       const float* __restrict__ convW,
                                                       u32* __restrict__ feats,
                                                       u32* __restrict__ wpk,
                                                       u32* __restrict__ cpk,
                                                       const float* __restrict__ sw,
                                                       const float* __restrict__ sb) {
    int idx = blockIdx.x * 256 + threadIdx.x;

    if (idx < MSD_DEPTH * NPAIR * 9) {
        int I = idx / (NPAIR * 9);
        int rem = idx - I * (NPAIR * 9);
        int p = rem / 9, t = rem - p * 9;
        int NC = I + 1, c0 = 2 * p, c1 = 2 * p + 1;
        h2v pk;
        pk[0] = (_Float16)((c0 < NC) ? Wmsd[((size_t)I * MSD_DEPTH + c0) * 9 + t] : 0.f);
        pk[1] = (_Float16)((c1 < NC) ? Wmsd[((size_t)I * MSD_DEPTH + c1) * 9 + t] : 0.f);
        wpk[idx] = __builtin_bit_cast(u32, pk);
    }
    if (idx < NPAIR) {
        h2v pk;
        pk[0] = (_Float16)convW[2 * idx];
        pk[1] = (_Float16)convW[2 * idx + 1];
        cpk[idx] = __builtin_bit_cast(u32, pk);
    }

    if (idx < ZSTRIPS) {
        const int per = 32 * (WPp / 4); // 32 rows x 136 uint4 strips = 4352
        int sub = idx / per;
        int s = idx - sub * per;
        int rr = s / 136;
        int c4 = (s - rr * 136) * 4;
        int r = (rr < 16) ? rr : (IH + HALO) + (rr - 16);
        uint4 z = {0, 0, 0, 0};
        *(uint4*)(feats + (size_t)sub * PLANE_U + (size_t)r * WPp + c4) = z;
    } else if (idx < TOTZ) {
        int s = idx - ZSTRIPS;
        int sub = s >> 12;            // / 4096 (= 512 rows * 8 strips)
        int rem = s & 4095;
        int r = HALO + (rem >> 3);    // 16..527
        int e = rem & 7;
        int c4 = (e < 4) ? (e * 4) : (IW + HALO + (e - 4) * 4);
        uint4 z = {0, 0, 0, 0};
        *(uint4*)(feats + (size_t)sub * PLANE_U + (size_t)r * WPp + c4) = z;
    }

    if (idx < NPIX / 8) {
        int pix = idx * 8;
        int b = pix >> 18;
        int y = (pix >> 9) & 511;
        int xx = pix & 511;
        const float sws = sw[0], sbs = sb[0];
        u32 v[8];
#pragma unroll
        for (int j = 0; j < 8; ++j) {
            _Float16 h = (_Float16)(x[pix + j] * sws + sbs);
            v[j] = (u32)__builtin_bit_cast(unsigned short, h);
        }
        u32* q = feats + (size_t)b * PLANE_U + (size_t)(y + HALO) * WPp + HALO + xx;
        *(uint4*)q = *(uint4*)&v[0];
        *(uint4*)(q + 4) = *(uint4*)&v[4];
    }
}

// ---------------------------------------------------------------------------
// Depth kernel: exact-union spans + named A/B pipeline + 8-row blocks.
// ---------------------------------------------------------------------------
template <int I>
__global__ __launch_bounds__(512, 2) void depth_kernel(u32* __restrict__ feats,
                                                       const u32* __restrict__ wpk,
                                                       const u32* __restrict__ cpk,
                                                       const float* __restrict__ bias,
                                                       const float* __restrict__ convW,
                                                       const float* __restrict__ convB,
                                                       const float* __restrict__ soutw,
                                                       const float* __restrict__ soutb,
                                                       float* __restrict__ out) {
    constexpr int D = (I % 10) + 1;
    constexpr int NC = I + 1;
    constexpr int NP = (NC + 1) / 2;
    constexpr bool LAST = (I == MSD_DEPTH - 1);
    constexpr int SPAN = 8 + 2 * D;     // exact union of the 3 tap windows
    constexpr int N4 = SPAN >> 2;       // full dwordx4 loads
    constexpr bool T2 = (SPAN & 3) != 0; // dwordx2 tail (odd D)

    const int tid = threadIdx.x;
    const int widx = tid >> 6, lane = tid & 63;
    const int bid = blockIdx.x; // 256 blocks x 8 waves = 2048 waves = rows
    // XCD band swizzle (validated R4-R8): 2 XCDs per image, contiguous bands.
    const int xcd = bid & 7;
    const int b = xcd >> 1;
    const int y = (xcd & 1) * 256 + (bid >> 3) * 8 + widx;

    // pb: dword col HALO + lane*8 (first output px of this lane).
    u32* const pb = feats + (size_t)b * PLANE_U + (size_t)(y + HALO) * WPp + HALO + lane * 8;

    float acc[8], ydot[8];
#pragma unroll
    for (int j = 0; j < 8; ++j) { acc[j] = 0.f; ydot[j] = 0.f; }

    const u32* const wrb = wpk + (size_t)I * (NPAIR * 9);

    // Named double buffers (SROA-promoted). Row span: dwords [-D, -D+SPAN)
    // relative to pb_row; taps: left=s[k], center=s[D+k], right=s[2D+k].
    u32 A[3][SPAN], B[3][SPAN];

    auto load_row = [&](u32* dst, const u32* rp) {
        const u32* src = rp - D;        // 4B-aligned; HW handles 16B-misalign
#pragma unroll
        for (int i = 0; i < N4; ++i)
            *(uint4*)&dst[4 * i] = *(const uint4*)(src + 4 * i);
        if constexpr (T2)
            *(uint2*)&dst[4 * N4] = *(const uint2*)(src + 4 * N4);
    };

    auto load_pair = [&](u32 (*bp)[SPAN], int p) {
        const u32* pp = pb + (size_t)p * PSTR;
        load_row(bp[0], pp - (ptrdiff_t)(D * WPp));
        load_row(bp[1], pp);
        load_row(bp[2], pp + (ptrdiff_t)(D * WPp));
    };

    auto compute = [&](u32 (*bp)[SPAN], int p) {
        const u32* wq = wrb + p * 9; // wave-uniform -> s_load
        const u32 cw = LAST ? cpk[p] : 0u;
#pragma unroll
        for (int r = 0; r < 3; ++r) {
            const u32* s = bp[r];
            const u32 w0 = wq[r * 3 + 0], w1 = wq[r * 3 + 1], w2 = wq[r * 3 + 2];
#pragma unroll
            for (int k = 0; k < 8; ++k) {
                float a = acc[k];
                a = fdot2u(s[k],         w0, a);   // left   (const idx)
                a = fdot2u(s[D + k],     w1, a);   // center
                a = fdot2u(s[2 * D + k], w2, a);   // right
                acc[k] = a;
            }
            if (LAST && r == 1) {
#pragma unroll
                for (int k = 0; k < 8; ++k) ydot[k] = fdot2u(s[D + k], cw, ydot[k]);
            }
        }
    };

    // 2-deep software pipeline over channel pairs (R12/R15-verified).
    load_pair(A, 0);
    int p = 0;
    for (; p + 2 <= NP; p += 2) {
        load_pair(B, p + 1);
        compute(A, p);
        if (p + 2 < NP) load_pair(A, p + 2);
        compute(B, p + 1);
    }
    if (p < NP) compute(A, p);

    const float b0 = bias[I];
    if (!LAST) {
        // Merge h (channel NC) into pair NC>>1. NC odd: hi16; partner lo16 =
        // channel NC-1 = center row of pair NP-1, still live in A or B regs.
        u32 part[8];
        if constexpr ((NC & 1) != 0) {
            constexpr bool inA = (((NP - 1) & 1) == 0);
            const u32* s = inA ? A[1] : B[1];
#pragma unroll
            for (int j = 0; j < 8; ++j) part[j] = s[D + j];
        }
        u32 mg[8];
#pragma unroll
        for (int j = 0; j < 8; ++j) {
            float h = acc[j] + b0;
            h = h > 0.f ? h : 0.f;
            u32 h16 = (u32)__builtin_bit_cast(unsigned short, (_Float16)h);
            if constexpr ((NC & 1) != 0)
                mg[j] = (part[j] & 0xFFFFu) | (h16 << 16);
            else
                mg[j] = h16;
        }
        u32* q = feats + (size_t)(NC >> 1) * PSTR + (size_t)b * PLANE_U +
                 (size_t)(y + HALO) * WPp + HALO + lane * 8;
        *(uint4*)q = *(uint4*)&mg[0];
        *(uint4*)(q + 4) = *(uint4*)&mg[4];
    } else {
        const float cw30 = convW[MSD_DEPTH];
        const float cb = convB[0], ow = soutw[0], ob = soutb[0];
        float* q = out + ((size_t)b * IH + y) * IW + lane * 8;
        float o[8];
#pragma unroll
        for (int j = 0; j < 8; ++j) {
            float h = acc[j] + b0;
            h = h > 0.f ? h : 0.f;
            float yv = ydot[j] + cw30 * h + cb;
            o[j] = yv * ow + ob;
        }
        *(uint4*)q = *(uint4*)&o[0];
        *(uint4*)(q + 4) = *(uint4*)&o[4];
    }
}

// ---------------------------------------------------------------------------
extern "C" void kernel_launch(void* const* d_in, const int* in_sizes, int n_in,
                              void* d_out, int out_size, void* d_ws, size_t ws_size,
                              hipStream_t stream) {
    const float* x     = (const float*)d_in[0];
    const float* Wmsd  = (const float*)d_in[1];
    const float* bias  = (const float*)d_in[2];
    const float* convW = (const float*)d_in[3];
    const float* convB = (const float*)d_in[4];
    const float* sinw  = (const float*)d_in[5];
    const float* sinb  = (const float*)d_in[6];
    const float* soutw = (const float*)d_in[7];
    const float* soutb = (const float*)d_in[8];
    float* out = (float*)d_out;

    u32* feats = (u32*)d_ws;                 // 15 pairs x 4 b x 544x544 u32 = 68 MB
    u32* wpk = feats + WPK_OFF;              // 80 MB offset
    u32* cpk = wpk + MSD_DEPTH * NPAIR * 9;

    preamble_kernel<<<(TOTZ + 255) / 256, 256, 0, stream>>>(x, Wmsd, convW,
                                                            feats, wpk, cpk,
                                                            sinw, sinb);

#define LNCH(I) depth_kernel<I><<<256, 512, 0, stream>>>(feats, wpk, cpk, bias, convW, convB, soutw, soutb, out);
    LNCH(0)  LNCH(1)  LNCH(2)  LNCH(3)  LNCH(4)
    LNCH(5)  LNCH(6)  LNCH(7)  LNCH(8)  LNCH(9)
    LNCH(10) LNCH(11) LNCH(12) LNCH(13) LNCH(14)
    LNCH(15) LNCH(16) LNCH(17) LNCH(18) LNCH(19)
    LNCH(20) LNCH(21) LNCH(22) LNCH(23) LNCH(24)
    LNCH(25) LNCH(26) LNCH(27) LNCH(28) LNCH(29)
#undef LNCH
}

// Round 6
// 380.596 us; speedup vs baseline: 3.6862x; 1.0514x over previous
//
#include <hip/hip_runtime.h>

// MSDNet on gfx950 — round 18. R17 post-mortem: traffic cuts (exact-union
// spans) were neutral-to-negative => depth kernels are NOT bandwidth-bound.
// Confirmed theory: latency-bound at 2 waves/SIMD (VALUBusy ~11%, occupancy
// 24%, grid-limited: 2048 row-waves / 256 CU). This round doubles TLP with
// BIT-IDENTICAL numerics: each row is split into two 256-px halves
// (4 px/lane) -> 4096 waves -> 512 blocks x 8 waves -> 2 blocks/CU ->
// 4 waves/SIMD. Same tap order per output px => exact same fp32 sum.
// __launch_bounds__(512,4) caps VGPR at 128 so the occupancy materializes.
// Aligned 16B chunk loads restored (R15-style, origin pb-12; R17's 4B-aligned
// exact-union loads likely split in the TA). Merge partner row from live regs.
// Layout: feats = 15 channel-pairs (u32 = 2xf16) x 4 batches x 544x544;
// fdot2 contracts 2 ch/px/tap; depth 29 fuses 1x1 conv + output affine.

#define MSD_DEPTH 30
#define NB 4
#define IH 512
#define IW 512
#define HALO 16
#define WPp (IW + 2 * HALO)               /* 544 u32 per row */
#define HPp (IH + 2 * HALO)               /* 544 rows */
#define PLANE_U ((size_t)WPp * HPp)       /* u32 per subplane */
#define PSTR ((size_t)NB * PLANE_U)       /* pair stride (u32) */
#define NPAIR 15
#define NPIX (NB * IH * IW)
#define WPK_OFF ((size_t)20 << 20)        /* u32 offset: 80 MB into ws */
#define ZSTRIPS (32 * (WPp / 4) * NPAIR * NB)   /* top/bot: 261120 uint4 */
#define SSTRIPS (512 * 8 * NPAIR * NB)          /* sides:   245760 uint4 */
#define TOTZ (ZSTRIPS + SSTRIPS)

typedef _Float16 h2v __attribute__((ext_vector_type(2)));
typedef unsigned int u32;

__device__ __forceinline__ float fdot2u(u32 a, u32 b, float c) {
#if __has_builtin(__builtin_amdgcn_fdot2)
    return __builtin_amdgcn_fdot2(__builtin_bit_cast(h2v, a),
                                  __builtin_bit_cast(h2v, b), c, false);
#else
    h2v x = __builtin_bit_cast(h2v, a), y = __builtin_bit_cast(h2v, b);
    return c + (float)x[0] * (float)y[0] + (float)x[1] * (float)y[1];
#endif
}

// ---------------------------------------------------------------------------
// Preamble: pack weights + zero halos (rows AND side cols) + scale input.
// ---------------------------------------------------------------------------
__global__ __launch_bounds__(256) void preamble_kernel(const float* __restrict__ x,
                                                       const float* __restrict__ Wmsd,
                                                       const float* __restrict__ convW,
                                                       u32* __restrict__ feats,
                                                       u32* __restrict__ wpk,
                                                       u32* __restrict__ cpk,
                                                       const float* __restrict__ sw,
                                                       const float* __restrict__ sb) {
    int idx = blockIdx.x * 256 + threadIdx.x;

    if (idx < MSD_DEPTH * NPAIR * 9) {
        int I = idx / (NPAIR * 9);
        int rem = idx - I * (NPAIR * 9);
        int p = rem / 9, t = rem - p * 9;
        int NC = I + 1, c0 = 2 * p, c1 = 2 * p + 1;
        h2v pk;
        pk[0] = (_Float16)((c0 < NC) ? Wmsd[((size_t)I * MSD_DEPTH + c0) * 9 + t] : 0.f);
        pk[1] = (_Float16)((c1 < NC) ? Wmsd[((size_t)I * MSD_DEPTH + c1) * 9 + t] : 0.f);
        wpk[idx] = __builtin_bit_cast(u32, pk);
    }
    if (idx < NPAIR) {
        h2v pk;
        pk[0] = (_Float16)convW[2 * idx];
        pk[1] = (_Float16)convW[2 * idx + 1];
        cpk[idx] = __builtin_bit_cast(u32, pk);
    }

    if (idx < ZSTRIPS) {
        const int per = 32 * (WPp / 4); // 32 rows x 136 uint4 strips = 4352
        int sub = idx / per;
        int s = idx - sub * per;
        int rr = s / 136;
        int c4 = (s - rr * 136) * 4;
        int r = (rr < 16) ? rr : (IH + HALO) + (rr - 16);
        uint4 z = {0, 0, 0, 0};
        *(uint4*)(feats + (size_t)sub * PLANE_U + (size_t)r * WPp + c4) = z;
    } else if (idx < TOTZ) {
        int s = idx - ZSTRIPS;
        int sub = s >> 12;            // / 4096 (= 512 rows * 8 strips)
        int rem = s & 4095;
        int r = HALO + (rem >> 3);    // 16..527
        int e = rem & 7;
        int c4 = (e < 4) ? (e * 4) : (IW + HALO + (e - 4) * 4);
        uint4 z = {0, 0, 0, 0};
        *(uint4*)(feats + (size_t)sub * PLANE_U + (size_t)r * WPp + c4) = z;
    }

    if (idx < NPIX / 8) {
        int pix = idx * 8;
        int b = pix >> 18;
        int y = (pix >> 9) & 511;
        int xx = pix & 511;
        const float sws = sw[0], sbs = sb[0];
        u32 v[8];
#pragma unroll
        for (int j = 0; j < 8; ++j) {
            _Float16 h = (_Float16)(x[pix + j] * sws + sbs);
            v[j] = (u32)__builtin_bit_cast(unsigned short, h);
        }
        u32* q = feats + (size_t)b * PLANE_U + (size_t)(y + HALO) * WPp + HALO + xx;
        *(uint4*)q = *(uint4*)&v[0];
        *(uint4*)(q + 4) = *(uint4*)&v[4];
    }
}

// ---------------------------------------------------------------------------
// Depth kernel: 4 px/lane (half-rows), 4 waves/SIMD, aligned chunk spans,
// named A/B 2-deep pair pipeline. Taps: s[12-D+k], s[12+k], s[12+D+k], k<4.
// ---------------------------------------------------------------------------
template <int I>
__global__ __launch_bounds__(512, 4) void depth_kernel(u32* __restrict__ feats,
                                                       const u32* __restrict__ wpk,
                                                       const u32* __restrict__ cpk,
                                                       const float* __restrict__ bias,
                                                       const float* __restrict__ convW,
                                                       const float* __restrict__ convB,
                                                       const float* __restrict__ soutw,
                                                       const float* __restrict__ soutb,
                                                       float* __restrict__ out) {
    constexpr int D = (I % 10) + 1;
    constexpr int NC = I + 1;
    constexpr int NP = (NC + 1) / 2;
    constexpr bool LAST = (I == MSD_DEPTH - 1);
    // Buffer origin pb-12 (16B-aligned). Needed dword indices [12-D, 15+D].
    constexpr int C0 = (12 - D) >> 2;   // D<=4 -> 2, D<=8 -> 1, else 0
    constexpr int C1 = (15 + D) >> 2;   // D<=4 -> 4, D<=8 -> 5, else 6
    constexpr int BW = 4 * (C1 + 1);    // buffer width (<= 28)

    const int tid = threadIdx.x;
    const int widx = tid >> 6, lane = tid & 63;   // widx 0..7
    const int bid = blockIdx.x;                   // 512 blocks x 8 waves
    // XCD band swizzle (validated R4-R8): 2 XCDs per image, contiguous bands.
    const int xcd = bid & 7;
    const int kk = bid >> 3;                      // 0..63
    const int b = xcd >> 1;
    const int y = (xcd & 1) * 256 + kk * 4 + (widx >> 1);
    const int h = widx & 1;                       // row half
    const int xx = h * 256 + lane * 4;            // first of 4 px

    // pb: dword col HALO + xx -> 16B-aligned; pb-12 also 16B-aligned.
    u32* const pb = feats + (size_t)b * PLANE_U + (size_t)(y + HALO) * WPp + HALO + xx;

    float acc[4], ydot[4];
#pragma unroll
    for (int j = 0; j < 4; ++j) { acc[j] = 0.f; ydot[j] = 0.f; }

    const u32* const wrb = wpk + (size_t)I * (NPAIR * 9);

    // Named double buffers (SROA-promoted; runtime-indexed rings go to scratch).
    u32 A[3][BW], B[3][BW];

    auto load_row = [&](u32* dst, const u32* rp) {
#pragma unroll
        for (int c = C0; c <= C1; ++c)
            *(uint4*)&dst[4 * c] = *(const uint4*)(rp - 12 + 4 * c);
    };

    auto load_pair = [&](u32 (*bp)[BW], int p) {
        const u32* pp = pb + (size_t)p * PSTR;
        load_row(bp[0], pp - (ptrdiff_t)(D * WPp));
        load_row(bp[1], pp);
        load_row(bp[2], pp + (ptrdiff_t)(D * WPp));
    };

    auto compute = [&](u32 (*bp)[BW], int p) {
        const u32* wq = wrb + p * 9; // wave-uniform -> s_load
        const u32 cw = LAST ? cpk[p] : 0u;
#pragma unroll
        for (int r = 0; r < 3; ++r) {
            const u32* s = bp[r];
            const u32 w0 = wq[r * 3 + 0], w1 = wq[r * 3 + 1], w2 = wq[r * 3 + 2];
#pragma unroll
            for (int k = 0; k < 4; ++k) {
                float a = acc[k];
                a = fdot2u(s[12 - D + k], w0, a);   // const idx taps
                a = fdot2u(s[12 + k],     w1, a);
                a = fdot2u(s[12 + D + k], w2, a);
                acc[k] = a;
            }
            if (LAST && r == 1) {
#pragma unroll
                for (int k = 0; k < 4; ++k) ydot[k] = fdot2u(s[12 + k], cw, ydot[k]);
            }
        }
    };

    // 2-deep software pipeline over channel pairs (R12/R15-verified).
    load_pair(A, 0);
    int p = 0;
    for (; p + 2 <= NP; p += 2) {
        load_pair(B, p + 1);
        compute(A, p);
        if (p + 2 < NP) load_pair(A, p + 2);
        compute(B, p + 1);
    }
    if (p < NP) compute(A, p);

    const float b0 = bias[I];
    if (!LAST) {
        // Merge h (channel NC) into pair NC>>1. NC odd: hi16; partner lo16 =
        // channel NC-1 = center row of pair NP-1, still live in A or B regs.
        u32 part[4];
        if constexpr ((NC & 1) != 0) {
            constexpr bool inA = (((NP - 1) & 1) == 0);
            const u32* s = inA ? A[1] : B[1];
#pragma unroll
            for (int j = 0; j < 4; ++j) part[j] = s[12 + j];
        }
        u32 mg[4];
#pragma unroll
        for (int j = 0; j < 4; ++j) {
            float hh = acc[j] + b0;
            hh = hh > 0.f ? hh : 0.f;
            u32 h16 = (u32)__builtin_bit_cast(unsigned short, (_Float16)hh);
            if constexpr ((NC & 1) != 0)
                mg[j] = (part[j] & 0xFFFFu) | (h16 << 16);
            else
                mg[j] = h16;
        }
        u32* q = feats + (size_t)(NC >> 1) * PSTR + (size_t)b * PLANE_U +
                 (size_t)(y + HALO) * WPp + HALO + xx;
        *(uint4*)q = *(uint4*)&mg[0];
    } else {
        const float cw30 = convW[MSD_DEPTH];
        const float cb = convB[0], ow = soutw[0], ob = soutb[0];
        float* q = out + ((size_t)b * IH + y) * IW + xx;
        float o[4];
#pragma unroll
        for (int j = 0; j < 4; ++j) {
            float hh = acc[j] + b0;
            hh = hh > 0.f ? hh : 0.f;
            float yv = ydot[j] + cw30 * hh + cb;
            o[j] = yv * ow + ob;
        }
        *(uint4*)q = *(uint4*)&o[0];
    }
}

// ---------------------------------------------------------------------------
extern "C" void kernel_launch(void* const* d_in, const int* in_sizes, int n_in,
                              void* d_out, int out_size, void* d_ws, size_t ws_size,
                              hipStream_t stream) {
    const float* x     = (const float*)d_in[0];
    const float* Wmsd  = (const float*)d_in[1];
    const float* bias  = (const float*)d_in[2];
    const float* convW = (const float*)d_in[3];
    const float* convB = (const float*)d_in[4];
    const float* sinw  = (const float*)d_in[5];
    const float* sinb  = (const float*)d_in[6];
    const float* soutw = (const float*)d_in[7];
    const float* soutb = (const float*)d_in[8];
    float* out = (float*)d_out;

    u32* feats = (u32*)d_ws;                 // 15 pairs x 4 b x 544x544 u32 = 68 MB
    u32* wpk = feats + WPK_OFF;              // 80 MB offset
    u32* cpk = wpk + MSD_DEPTH * NPAIR * 9;

    preamble_kernel<<<(TOTZ + 255) / 256, 256, 0, stream>>>(x, Wmsd, convW,
                                                            feats, wpk, cpk,
                                                            sinw, sinb);

#define LNCH(I) depth_kernel<I><<<512, 512, 0, stream>>>(feats, wpk, cpk, bias, convW, convB, soutw, soutb, out);
    LNCH(0)  LNCH(1)  LNCH(2)  LNCH(3)  LNCH(4)
    LNCH(5)  LNCH(6)  LNCH(7)  LNCH(8)  LNCH(9)
    LNCH(10) LNCH(11) LNCH(12) LNCH(13) LNCH(14)
    LNCH(15) LNCH(16) LNCH(17) LNCH(18) LNCH(19)
    LNCH(20) LNCH(21) LNCH(22) LNCH(23) LNCH(24)
    LNCH(25) LNCH(26) LNCH(27) LNCH(28) LNCH(29)
#undef LNCH
}